// Round 5
// baseline (82.716 us; speedup 1.0000x reference)
//
#include <hip/hip_runtime.h>
#include <math.h>

#define DIM 4096
#define H 32
#define D 128
#define SMAX 2048
#define CHUNK 32
#define NCHUNK (SMAX / CHUNK)   // 64
#define PART_STRIDE 130         // m, l, acc[128]

typedef float v4f __attribute__((ext_vector_type(4)));

// load 8 float4 (half a row: 2048 floats across 64 lanes) into regs
__device__ __forceinline__ void load_half(v4f (&buf)[8], const float* __restrict__ wp, int off) {
#pragma unroll
    for (int i = 0; i < 8; ++i)
        buf[i] = *reinterpret_cast<const v4f*>(wp + i * 256 + off);
}

template <int XO>   // xr offset: 0 = low half, 8 = high half
__device__ __forceinline__ float dot_half(const v4f (&buf)[8], const v4f (&xr)[16]) {
    float s0 = 0.f, s1 = 0.f, s2 = 0.f, s3 = 0.f;
#pragma unroll
    for (int i = 0; i < 8; ++i) {
        s0 = fmaf(buf[i].x, xr[XO + i].x, s0);
        s1 = fmaf(buf[i].y, xr[XO + i].y, s1);
        s2 = fmaf(buf[i].z, xr[XO + i].z, s2);
        s3 = fmaf(buf[i].w, xr[XO + i].w, s3);
    }
    return (s0 + s1) + (s2 + s3);
}

__device__ __forceinline__ float wave_sum(float v) {
#pragma unroll
    for (int o = 32; o; o >>= 1) v += __shfl_xor(v, o);
    return v;
}

#define SB() __builtin_amdgcn_sched_barrier(0)

// ---------------- fused QKV matvec + RoPE ----------------
// grid 512 x 256; wave W (0..2047) computes rows 2W,2W+1 of wq,wk,wv (6 dots),
// applies RoPE to the q/k row-pairs, writes xq/xk/xv. 12 pipelined half-row
// phases, A/B double buffer, x held in registers for the whole wave lifetime.
__global__ void __launch_bounds__(256) qkv_rope(
        const float* __restrict__ wq, const float* __restrict__ wk,
        const float* __restrict__ wv, const float* __restrict__ x,
        const int* __restrict__ pos_p,
        float* __restrict__ xq, float* __restrict__ xk, float* __restrict__ xv) {
    int t = threadIdx.x, lane = t & 63;
    int W = blockIdx.x * 4 + (t >> 6);      // 0..2047
    int r0 = W * 2;
    int off = lane * 4;

    v4f xr[16];
#pragma unroll
    for (int i = 0; i < 16; ++i)
        xr[i] = *reinterpret_cast<const v4f*>(x + i * 256 + off);

    const float* q0 = wq + (size_t)r0 * DIM;
    const float* k0 = wk + (size_t)r0 * DIM;
    const float* v0 = wv + (size_t)r0 * DIM;

    v4f A[8], B[8];
    float dq0, dq1, dk0, dk1, dv0, dv1;

    load_half(A, q0, off);                                // q0 lo
    load_half(B, q0 + 2048, off);            SB();        // q0 hi
    dq0  = dot_half<0>(A, xr);
    load_half(A, q0 + DIM, off);             SB();        // q1 lo
    dq0 += dot_half<8>(B, xr);
    load_half(B, q0 + DIM + 2048, off);      SB();        // q1 hi
    dq1  = dot_half<0>(A, xr);
    load_half(A, k0, off);                   SB();        // k0 lo
    dq1 += dot_half<8>(B, xr);
    load_half(B, k0 + 2048, off);            SB();        // k0 hi
    dk0  = dot_half<0>(A, xr);
    load_half(A, k0 + DIM, off);             SB();        // k1 lo
    dk0 += dot_half<8>(B, xr);
    load_half(B, k0 + DIM + 2048, off);      SB();        // k1 hi
    dk1  = dot_half<0>(A, xr);
    load_half(A, v0, off);                   SB();        // v0 lo
    dk1 += dot_half<8>(B, xr);
    load_half(B, v0 + 2048, off);            SB();        // v0 hi
    dv0  = dot_half<0>(A, xr);
    load_half(A, v0 + DIM, off);             SB();        // v1 lo
    dv0 += dot_half<8>(B, xr);
    load_half(B, v0 + DIM + 2048, off);      SB();        // v1 hi
    dv1  = dot_half<0>(A, xr);
    dv1 += dot_half<8>(B, xr);

    dq0 = wave_sum(dq0); dq1 = wave_sum(dq1);
    dk0 = wave_sum(dk0); dk1 = wave_sum(dk1);
    dv0 = wave_sum(dv0); dv1 = wave_sum(dv1);

    if (lane == 0) {
        int pos = *pos_p;
        int j = W & 63;                      // RoPE pair index within head
        float theta = powf(10000.0f, -(float)(2 * j) / (float)D);
        float ang = (float)pos * theta;
        float s, c;
        sincosf(ang, &s, &c);
        xq[r0]     = dq0 * c - dq1 * s;
        xq[r0 + 1] = dq0 * s + dq1 * c;
        xk[r0]     = dk0 * c - dk1 * s;
        xk[r0 + 1] = dk0 * s + dk1 * c;
        xv[r0]     = dv0;
        xv[r0 + 1] = dv1;
    }
}

// ---------------- out = Wo @ v : wave per row-pair, 4 pipelined phases ----------------
__global__ void __launch_bounds__(256) matvec_o(
        const float* __restrict__ w_, const float* __restrict__ vin,
        float* __restrict__ y) {
    int t = threadIdx.x, lane = t & 63;
    int W = blockIdx.x * 4 + (t >> 6);      // 0..2047
    int r0 = W * 2;
    int off = lane * 4;

    v4f xr[16];
#pragma unroll
    for (int i = 0; i < 16; ++i)
        xr[i] = *reinterpret_cast<const v4f*>(vin + i * 256 + off);

    const float* w0 = w_ + (size_t)r0 * DIM;

    v4f A[8], B[8];
    float d0, d1;
    load_half(A, w0, off);
    load_half(B, w0 + 2048, off);            SB();
    d0  = dot_half<0>(A, xr);
    load_half(A, w0 + DIM, off);             SB();
    d0 += dot_half<8>(B, xr);
    load_half(B, w0 + DIM + 2048, off);      SB();
    d1  = dot_half<0>(A, xr);
    d1 += dot_half<8>(B, xr);

    d0 = wave_sum(d0); d1 = wave_sum(d1);
    if (lane == 0) { y[r0] = d0; y[r0 + 1] = d1; }
}

// ---------------- flash-decode partials ----------------
__global__ void attn_partial(const float* __restrict__ cache_k, const float* __restrict__ cache_v,
                             const float* __restrict__ xq, const float* __restrict__ xk,
                             const float* __restrict__ xv, const int* __restrict__ pos_p,
                             float* __restrict__ partials) {
    __shared__ float lds_m[4], lds_l[4];
    __shared__ float lds_acc[4][128];
    int h = blockIdx.x;
    int c = blockIdx.y;
    int lane = threadIdx.x;          // 64
    int g  = lane >> 4;              // group 0..3
    int gl = lane & 15;              // lane-in-group; owns dims gl*8 .. gl*8+7
    int pos = *pos_p;
    int base = c * CHUNK;
    int p1 = min(base + CHUNK, pos + 1);
    float* pp = partials + (size_t)(h * NCHUNK + c) * PART_STRIDE;

    if (base > pos) {   // fully inactive chunk: identity partial
        if (lane == 0) { pp[0] = -INFINITY; pp[1] = 0.f; }
        reinterpret_cast<float2*>(pp + 2)[lane] = make_float2(0.f, 0.f);
        return;
    }

    const float4* qv = reinterpret_cast<const float4*>(xq + h * D + gl * 8);
    const float4 q0 = qv[0], q1 = qv[1];

    float m = -INFINITY, l = 0.f;
    float4 acc0 = make_float4(0.f, 0.f, 0.f, 0.f);
    float4 acc1 = make_float4(0.f, 0.f, 0.f, 0.f);

    for (int p = base + g; p < p1; p += 4) {
        const float* kp = (p == pos) ? (xk + h * D)
                                     : (cache_k + ((size_t)p * H + h) * D);
        const float4* kv4 = reinterpret_cast<const float4*>(kp + gl * 8);
        float4 k0 = kv4[0], k1 = kv4[1];
        float d = q0.x * k0.x + q0.y * k0.y + q0.z * k0.z + q0.w * k0.w
                + q1.x * k1.x + q1.y * k1.y + q1.z * k1.z + q1.w * k1.w;
        d += __shfl_xor(d, 1);
        d += __shfl_xor(d, 2);
        d += __shfl_xor(d, 4);
        d += __shfl_xor(d, 8);       // all 16 lanes of the group hold the dot
        float s = d * 0.08838834764831845f;   // 1/sqrt(128)
        float mn = fmaxf(m, s);
        float corr = __expf(m - mn);          // exp(-inf)=0 on first iter
        float wgt  = __expf(s - mn);
        const float* vp = (p == pos) ? (xv + h * D)
                                     : (cache_v + ((size_t)p * H + h) * D);
        const float4* vv4 = reinterpret_cast<const float4*>(vp + gl * 8);
        float4 v0 = vv4[0], v1 = vv4[1];
        l = l * corr + wgt;
        acc0.x = fmaf(wgt, v0.x, acc0.x * corr);
        acc0.y = fmaf(wgt, v0.y, acc0.y * corr);
        acc0.z = fmaf(wgt, v0.z, acc0.z * corr);
        acc0.w = fmaf(wgt, v0.w, acc0.w * corr);
        acc1.x = fmaf(wgt, v1.x, acc1.x * corr);
        acc1.y = fmaf(wgt, v1.y, acc1.y * corr);
        acc1.z = fmaf(wgt, v1.z, acc1.z * corr);
        acc1.w = fmaf(wgt, v1.w, acc1.w * corr);
        m = mn;
    }

    // combine the 4 groups inside the block
    if (gl == 0) { lds_m[g] = m; lds_l[g] = l; }
    *reinterpret_cast<float4*>(&lds_acc[g][gl * 8])     = acc0;
    *reinterpret_cast<float4*>(&lds_acc[g][gl * 8 + 4]) = acc1;
    __syncthreads();
    float M = fmaxf(fmaxf(lds_m[0], lds_m[1]), fmaxf(lds_m[2], lds_m[3]));
    float w0 = __expf(lds_m[0] - M);
    float w1 = __expf(lds_m[1] - M);
    float w2 = __expf(lds_m[2] - M);
    float w3 = __expf(lds_m[3] - M);
    float L  = w0 * lds_l[0] + w1 * lds_l[1] + w2 * lds_l[2] + w3 * lds_l[3];
    int d0 = 2 * lane;
    float s0 = w0 * lds_acc[0][d0]     + w1 * lds_acc[1][d0]
             + w2 * lds_acc[2][d0]     + w3 * lds_acc[3][d0];
    float s1 = w0 * lds_acc[0][d0 + 1] + w1 * lds_acc[1][d0 + 1]
             + w2 * lds_acc[2][d0 + 1] + w3 * lds_acc[3][d0 + 1];
    if (lane == 0) { pp[0] = M; pp[1] = L; }
    reinterpret_cast<float2*>(pp + 2)[lane] = make_float2(s0, s1);
}

// ---------------- combine partials per head ----------------
__global__ void attn_combine(const float* __restrict__ partials, float* __restrict__ out_attn) {
    int h = blockIdx.x;
    int lane = threadIdx.x;          // 64 lanes, dims 2*lane, 2*lane+1
    float m = -INFINITY;
    for (int c = 0; c < NCHUNK; ++c)
        m = fmaxf(m, partials[(size_t)(h * NCHUNK + c) * PART_STRIDE]);
    float L = 0.f, a0 = 0.f, a1 = 0.f;
    for (int c = 0; c < NCHUNK; ++c) {
        const float* pp = partials + (size_t)(h * NCHUNK + c) * PART_STRIDE;
        float w = __expf(pp[0] - m);      // exp(-inf - m) = 0 for empty chunks
        L += pp[1] * w;
        float2 a = reinterpret_cast<const float2*>(pp + 2)[lane];
        a0 += w * a.x;
        a1 += w * a.y;
    }
    float inv = 1.f / L;
    out_attn[h * D + 2 * lane]     = a0 * inv;
    out_attn[h * D + 2 * lane + 1] = a1 * inv;
}

extern "C" void kernel_launch(void* const* d_in, const int* in_sizes, int n_in,
                              void* d_out, int out_size, void* d_ws, size_t ws_size,
                              hipStream_t stream) {
    const float* x       = (const float*)d_in[0];
    const float* wq      = (const float*)d_in[1];
    const float* wk      = (const float*)d_in[2];
    const float* wv      = (const float*)d_in[3];
    const float* wo      = (const float*)d_in[4];
    const float* cache_k = (const float*)d_in[5];
    const float* cache_v = (const float*)d_in[6];
    const int*   pos     = (const int*)d_in[7];

    float* ws       = (float*)d_ws;
    float* xq       = ws;                 // 4096
    float* xk       = ws + DIM;           // 4096
    float* xv       = ws + 2 * DIM;       // 4096
    float* partials = ws + 3 * DIM;       // 32*64*130
    float* out_attn = partials + H * NCHUNK * PART_STRIDE;  // 4096
    float* out      = (float*)d_out;

    qkv_rope<<<512, 256, 0, stream>>>(wq, wk, wv, x, pos, xq, xk, xv);
    attn_partial<<<dim3(H, NCHUNK), 64, 0, stream>>>(cache_k, cache_v, xq, xk, xv, pos, partials);
    attn_combine<<<H, 64, 0, stream>>>(partials, out_attn);
    matvec_o<<<512, 256, 0, stream>>>(wo, out_attn, out);
}

// Round 6
// 80.473 us; speedup vs baseline: 1.0279x; 1.0279x over previous
//
#include <hip/hip_runtime.h>
#include <math.h>

#define DIM 4096
#define H 32
#define D 128
#define SMAX 2048
#define CHUNK 32
#define NCHUNK (SMAX / CHUNK)   // 64
#define PART_STRIDE 130         // m, l, acc[128]

typedef float v4f __attribute__((ext_vector_type(4)));

__device__ __forceinline__ float wave_sum(float v) {
#pragma unroll
    for (int o = 32; o; o >>= 1) v += __shfl_xor(v, o);
    return v;
}

// ---------------- B: persistent grid-stride row-pair kernel for wq & wk + RoPE ----------------
// 2048 blocks x 256 thr (~8 blocks/CU). Task tp in [0,4096): tp<2048 -> q-pair, else k-pair.
// x cached in 4 v4f registers for the whole block lifetime. 8 float4 w-loads per
// iteration (2 rows), LDS reduce (parity-alternated buffers, 1 barrier/iter), RoPE at end.
__global__ void __launch_bounds__(256) qk_rope(
        const float* __restrict__ wq, const float* __restrict__ wk,
        const float* __restrict__ x, const int* __restrict__ pos_p,
        float* __restrict__ xq, float* __restrict__ xk) {
    __shared__ float red[2][2][4];            // [parity][row01][wave]
    int t = threadIdx.x, lane = t & 63, wv_ = t >> 6;
    int pos = *pos_p;

    v4f xr[4];
#pragma unroll
    for (int i = 0; i < 4; ++i)
        xr[i] = *reinterpret_cast<const v4f*>(x + i * 1024 + t * 4);

    int par = 0;
    for (int tp = blockIdx.x; tp < 4096; tp += gridDim.x, par ^= 1) {
        bool isq = tp < 2048;
        int pr = isq ? tp : tp - 2048;        // pair index within matrix
        const float* base = (isq ? wq : wk) + (size_t)pr * 2 * DIM;

        v4f wa[4], wb[4];
#pragma unroll
        for (int i = 0; i < 4; ++i) {
            wa[i] = *reinterpret_cast<const v4f*>(base + i * 1024 + t * 4);
            wb[i] = *reinterpret_cast<const v4f*>(base + DIM + i * 1024 + t * 4);
        }
        float a0 = 0.f, a1 = 0.f, a2 = 0.f, a3 = 0.f;
        float b0 = 0.f, b1 = 0.f, b2 = 0.f, b3 = 0.f;
#pragma unroll
        for (int i = 0; i < 4; ++i) {
            a0 = fmaf(wa[i].x, xr[i].x, a0);
            a1 = fmaf(wa[i].y, xr[i].y, a1);
            a2 = fmaf(wa[i].z, xr[i].z, a2);
            a3 = fmaf(wa[i].w, xr[i].w, a3);
            b0 = fmaf(wb[i].x, xr[i].x, b0);
            b1 = fmaf(wb[i].y, xr[i].y, b1);
            b2 = fmaf(wb[i].z, xr[i].z, b2);
            b3 = fmaf(wb[i].w, xr[i].w, b3);
        }
        float da = wave_sum((a0 + a1) + (a2 + a3));
        float db = wave_sum((b0 + b1) + (b2 + b3));
        if (lane == 0) { red[par][0][wv_] = da; red[par][1][wv_] = db; }
        __syncthreads();
        if (t == 0) {
            float d0 = red[par][0][0] + red[par][0][1] + red[par][0][2] + red[par][0][3];
            float d1 = red[par][1][0] + red[par][1][1] + red[par][1][2] + red[par][1][3];
            int j = pr & 63;                  // RoPE pair index within head
            float theta = powf(10000.0f, -(float)(2 * j) / (float)D);
            float ang = (float)pos * theta;
            float s, c;
            sincosf(ang, &s, &c);
            float* o = isq ? xq : xk;
            o[2 * pr]     = d0 * c - d1 * s;
            o[2 * pr + 1] = d0 * s + d1 * c;
        }
        // no second barrier: parity-alternated red buffers
    }
}

// ---------------- A (control, R1 structure): block-per-row for wv ----------------
__global__ void __launch_bounds__(256) v_mat(
        const float* __restrict__ wv, const float* __restrict__ x,
        float* __restrict__ xv) {
    __shared__ float red[4];
    int row = blockIdx.x;
    const float* w = wv + (size_t)row * DIM;
    int t = threadIdx.x;
    float acc = 0.f;
#pragma unroll
    for (int i = 0; i < 4; ++i) {
        int idx = (i * 256 + t) * 4;
        const float4 a = *reinterpret_cast<const float4*>(w + idx);
        const float4 b = *reinterpret_cast<const float4*>(x + idx);
        acc = fmaf(a.x, b.x, acc);
        acc = fmaf(a.y, b.y, acc);
        acc = fmaf(a.z, b.z, acc);
        acc = fmaf(a.w, b.w, acc);
    }
#pragma unroll
    for (int off = 32; off; off >>= 1) acc += __shfl_xor(acc, off);
    if ((t & 63) == 0) red[t >> 6] = acc;
    __syncthreads();
    if (t == 0) xv[row] = red[0] + red[1] + red[2] + red[3];
}

// ---------------- out = Wo @ v : wave per row-pair, pipelined (L3-resident, fast) ----------------
__device__ __forceinline__ void load_half(v4f (&buf)[8], const float* __restrict__ wp, int off) {
#pragma unroll
    for (int i = 0; i < 8; ++i)
        buf[i] = *reinterpret_cast<const v4f*>(wp + i * 256 + off);
}

template <int XO>
__device__ __forceinline__ float dot_half(const v4f (&buf)[8], const v4f (&xr)[16]) {
    float s0 = 0.f, s1 = 0.f, s2 = 0.f, s3 = 0.f;
#pragma unroll
    for (int i = 0; i < 8; ++i) {
        s0 = fmaf(buf[i].x, xr[XO + i].x, s0);
        s1 = fmaf(buf[i].y, xr[XO + i].y, s1);
        s2 = fmaf(buf[i].z, xr[XO + i].z, s2);
        s3 = fmaf(buf[i].w, xr[XO + i].w, s3);
    }
    return (s0 + s1) + (s2 + s3);
}

#define SB() __builtin_amdgcn_sched_barrier(0)

__global__ void __launch_bounds__(256) matvec_o(
        const float* __restrict__ w_, const float* __restrict__ vin,
        float* __restrict__ y) {
    int t = threadIdx.x, lane = t & 63;
    int W = blockIdx.x * 4 + (t >> 6);      // 0..2047
    int r0 = W * 2;
    int off = lane * 4;

    v4f xr[16];
#pragma unroll
    for (int i = 0; i < 16; ++i)
        xr[i] = *reinterpret_cast<const v4f*>(vin + i * 256 + off);

    const float* w0 = w_ + (size_t)r0 * DIM;
    v4f A[8], B[8];
    float d0, d1;
    load_half(A, w0, off);
    load_half(B, w0 + 2048, off);            SB();
    d0  = dot_half<0>(A, xr);
    load_half(A, w0 + DIM, off);             SB();
    d0 += dot_half<8>(B, xr);
    load_half(B, w0 + DIM + 2048, off);      SB();
    d1  = dot_half<0>(A, xr);
    d1 += dot_half<8>(B, xr);

    d0 = wave_sum(d0); d1 = wave_sum(d1);
    if (lane == 0) { y[r0] = d0; y[r0 + 1] = d1; }
}

// ---------------- flash-decode partials ----------------
__global__ void attn_partial(const float* __restrict__ cache_k, const float* __restrict__ cache_v,
                             const float* __restrict__ xq, const float* __restrict__ xk,
                             const float* __restrict__ xv, const int* __restrict__ pos_p,
                             float* __restrict__ partials) {
    __shared__ float lds_m[4], lds_l[4];
    __shared__ float lds_acc[4][128];
    int h = blockIdx.x;
    int c = blockIdx.y;
    int lane = threadIdx.x;          // 64
    int g  = lane >> 4;              // group 0..3
    int gl = lane & 15;              // lane-in-group; owns dims gl*8 .. gl*8+7
    int pos = *pos_p;
    int base = c * CHUNK;
    int p1 = min(base + CHUNK, pos + 1);
    float* pp = partials + (size_t)(h * NCHUNK + c) * PART_STRIDE;

    if (base > pos) {   // fully inactive chunk: identity partial
        if (lane == 0) { pp[0] = -INFINITY; pp[1] = 0.f; }
        reinterpret_cast<float2*>(pp + 2)[lane] = make_float2(0.f, 0.f);
        return;
    }

    const float4* qv = reinterpret_cast<const float4*>(xq + h * D + gl * 8);
    const float4 q0 = qv[0], q1 = qv[1];

    float m = -INFINITY, l = 0.f;
    float4 acc0 = make_float4(0.f, 0.f, 0.f, 0.f);
    float4 acc1 = make_float4(0.f, 0.f, 0.f, 0.f);

    for (int p = base + g; p < p1; p += 4) {
        const float* kp = (p == pos) ? (xk + h * D)
                                     : (cache_k + ((size_t)p * H + h) * D);
        const float4* kv4 = reinterpret_cast<const float4*>(kp + gl * 8);
        float4 k0 = kv4[0], k1 = kv4[1];
        float d = q0.x * k0.x + q0.y * k0.y + q0.z * k0.z + q0.w * k0.w
                + q1.x * k1.x + q1.y * k1.y + q1.z * k1.z + q1.w * k1.w;
        d += __shfl_xor(d, 1);
        d += __shfl_xor(d, 2);
        d += __shfl_xor(d, 4);
        d += __shfl_xor(d, 8);       // all 16 lanes of the group hold the dot
        float s = d * 0.08838834764831845f;   // 1/sqrt(128)
        float mn = fmaxf(m, s);
        float corr = __expf(m - mn);          // exp(-inf)=0 on first iter
        float wgt  = __expf(s - mn);
        const float* vp = (p == pos) ? (xv + h * D)
                                     : (cache_v + ((size_t)p * H + h) * D);
        const float4* vv4 = reinterpret_cast<const float4*>(vp + gl * 8);
        float4 v0 = vv4[0], v1 = vv4[1];
        l = l * corr + wgt;
        acc0.x = fmaf(wgt, v0.x, acc0.x * corr);
        acc0.y = fmaf(wgt, v0.y, acc0.y * corr);
        acc0.z = fmaf(wgt, v0.z, acc0.z * corr);
        acc0.w = fmaf(wgt, v0.w, acc0.w * corr);
        acc1.x = fmaf(wgt, v1.x, acc1.x * corr);
        acc1.y = fmaf(wgt, v1.y, acc1.y * corr);
        acc1.z = fmaf(wgt, v1.z, acc1.z * corr);
        acc1.w = fmaf(wgt, v1.w, acc1.w * corr);
        m = mn;
    }

    // combine the 4 groups inside the block
    if (gl == 0) { lds_m[g] = m; lds_l[g] = l; }
    *reinterpret_cast<float4*>(&lds_acc[g][gl * 8])     = acc0;
    *reinterpret_cast<float4*>(&lds_acc[g][gl * 8 + 4]) = acc1;
    __syncthreads();
    float M = fmaxf(fmaxf(lds_m[0], lds_m[1]), fmaxf(lds_m[2], lds_m[3]));
    float w0 = __expf(lds_m[0] - M);
    float w1 = __expf(lds_m[1] - M);
    float w2 = __expf(lds_m[2] - M);
    float w3 = __expf(lds_m[3] - M);
    float L  = w0 * lds_l[0] + w1 * lds_l[1] + w2 * lds_l[2] + w3 * lds_l[3];
    int d0 = 2 * lane;
    float s0 = w0 * lds_acc[0][d0]     + w1 * lds_acc[1][d0]
             + w2 * lds_acc[2][d0]     + w3 * lds_acc[3][d0];
    float s1 = w0 * lds_acc[0][d0 + 1] + w1 * lds_acc[1][d0 + 1]
             + w2 * lds_acc[2][d0 + 1] + w3 * lds_acc[3][d0 + 1];
    if (lane == 0) { pp[0] = M; pp[1] = L; }
    reinterpret_cast<float2*>(pp + 2)[lane] = make_float2(s0, s1);
}

// ---------------- combine partials per head ----------------
__global__ void attn_combine(const float* __restrict__ partials, float* __restrict__ out_attn) {
    int h = blockIdx.x;
    int lane = threadIdx.x;          // 64 lanes, dims 2*lane, 2*lane+1
    float m = -INFINITY;
    for (int c = 0; c < NCHUNK; ++c)
        m = fmaxf(m, partials[(size_t)(h * NCHUNK + c) * PART_STRIDE]);
    float L = 0.f, a0 = 0.f, a1 = 0.f;
    for (int c = 0; c < NCHUNK; ++c) {
        const float* pp = partials + (size_t)(h * NCHUNK + c) * PART_STRIDE;
        float w = __expf(pp[0] - m);      // exp(-inf - m) = 0 for empty chunks
        L += pp[1] * w;
        float2 a = reinterpret_cast<const float2*>(pp + 2)[lane];
        a0 += w * a.x;
        a1 += w * a.y;
    }
    float inv = 1.f / L;
    out_attn[h * D + 2 * lane]     = a0 * inv;
    out_attn[h * D + 2 * lane + 1] = a1 * inv;
}

extern "C" void kernel_launch(void* const* d_in, const int* in_sizes, int n_in,
                              void* d_out, int out_size, void* d_ws, size_t ws_size,
                              hipStream_t stream) {
    const float* x       = (const float*)d_in[0];
    const float* wq      = (const float*)d_in[1];
    const float* wk      = (const float*)d_in[2];
    const float* wv      = (const float*)d_in[3];
    const float* wo      = (const float*)d_in[4];
    const float* cache_k = (const float*)d_in[5];
    const float* cache_v = (const float*)d_in[6];
    const int*   pos     = (const int*)d_in[7];

    float* ws       = (float*)d_ws;
    float* xq       = ws;                 // 4096
    float* xk       = ws + DIM;           // 4096
    float* xv       = ws + 2 * DIM;       // 4096
    float* partials = ws + 3 * DIM;       // 32*64*130
    float* out_attn = partials + H * NCHUNK * PART_STRIDE;  // 4096
    float* out      = (float*)d_out;

    qk_rope<<<2048, 256, 0, stream>>>(wq, wk, x, pos, xq, xk);
    v_mat<<<DIM, 256, 0, stream>>>(wv, x, xv);
    attn_partial<<<dim3(H, NCHUNK), 64, 0, stream>>>(cache_k, cache_v, xq, xk, xv, pos, partials);
    attn_combine<<<H, 64, 0, stream>>>(partials, out_attn);
    matvec_o<<<512, 256, 0, stream>>>(wo, out_attn, out);
}

// Round 7
// 78.561 us; speedup vs baseline: 1.0529x; 1.0243x over previous
//
#include <hip/hip_runtime.h>
#include <math.h>

#define DIM 4096
#define H 32
#define D 128
#define SMAX 2048
#define CHUNK 32
#define NCHUNK (SMAX / CHUNK)   // 64
#define PART_STRIDE 130         // m, l, acc[128]

typedef float v4f __attribute__((ext_vector_type(4)));
typedef unsigned int u32;

__device__ __forceinline__ float wave_sum(float v) {
#pragma unroll
    for (int o = 32; o; o >>= 1) v += __shfl_xor(v, o);
    return v;
}

// async DMA global->LDS, 16 bytes per lane
__device__ __forceinline__ void gload_lds16(const float* g, float* l) {
    __builtin_amdgcn_global_load_lds(
        (const __attribute__((address_space(1))) u32*)g,
        (__attribute__((address_space(3))) u32*)l, 16, 0, 0);
}

// ---------------- qk matvec + RoPE via global_load_lds staging ----------------
// 4096 blocks x 256 thr. Block b: pair pr=b&2047 of (b<2048 ? wq : wk).
// Stage 2 contiguous rows (32 KB) into LDS via DMA path, then FMA from LDS.
__global__ void __launch_bounds__(256) qk_rope(
        const float* __restrict__ wq, const float* __restrict__ wk,
        const float* __restrict__ x, const int* __restrict__ pos_p,
        float* __restrict__ xq, float* __restrict__ xk) {
    __shared__ float buf[2 * DIM];            // 32 KB: row0 | row1
    __shared__ float red[2][4];
    int t = threadIdx.x, lane = t & 63, w = t >> 6;
    int bid = blockIdx.x;
    bool isq = bid < 2048;
    int pr = bid & 2047;
    const float* base = (isq ? wq : wk) + (size_t)pr * 2 * DIM;

    // x chunk for this thread (VGPR path, tiny, L2-hit)
    v4f xr[4];
#pragma unroll
    for (int i = 0; i < 4; ++i)
        xr[i] = *reinterpret_cast<const v4f*>(x + i * 1024 + t * 4);

    // stage 32 KB: 8 issues/thread of 16 B. LDS dest is linear in thread order:
    // byte (i*1024 + t*4)*4 = i*4096 + w*1024 + lane*16  (wave-uniform base + lane*16)
#pragma unroll
    for (int i = 0; i < 8; ++i)
        gload_lds16(base + i * 1024 + t * 4, &buf[i * 1024 + t * 4]);

    __syncthreads();   // drains vmcnt: staging complete, x regs ready

    float a0 = 0.f, a1 = 0.f, a2 = 0.f, a3 = 0.f;
    float b0 = 0.f, b1 = 0.f, b2 = 0.f, b3 = 0.f;
#pragma unroll
    for (int i = 0; i < 4; ++i) {
        v4f ra = *reinterpret_cast<v4f*>(&buf[i * 1024 + t * 4]);
        v4f rb = *reinterpret_cast<v4f*>(&buf[DIM + i * 1024 + t * 4]);
        a0 = fmaf(ra.x, xr[i].x, a0);
        a1 = fmaf(ra.y, xr[i].y, a1);
        a2 = fmaf(ra.z, xr[i].z, a2);
        a3 = fmaf(ra.w, xr[i].w, a3);
        b0 = fmaf(rb.x, xr[i].x, b0);
        b1 = fmaf(rb.y, xr[i].y, b1);
        b2 = fmaf(rb.z, xr[i].z, b2);
        b3 = fmaf(rb.w, xr[i].w, b3);
    }
    float da = wave_sum((a0 + a1) + (a2 + a3));
    float db = wave_sum((b0 + b1) + (b2 + b3));
    if (lane == 0) { red[0][w] = da; red[1][w] = db; }
    __syncthreads();
    if (t == 0) {
        float d0 = red[0][0] + red[0][1] + red[0][2] + red[0][3];
        float d1 = red[1][0] + red[1][1] + red[1][2] + red[1][3];
        int pos = *pos_p;
        int j = pr & 63;                  // RoPE pair index within head
        float theta = powf(10000.0f, -(float)(2 * j) / (float)D);
        float ang = (float)pos * theta;
        float s, c;
        sincosf(ang, &s, &c);
        float* o = isq ? xq : xk;
        o[2 * pr]     = d0 * c - d1 * s;
        o[2 * pr + 1] = d0 * s + d1 * c;
    }
}

// ---------------- A (control, R1 structure): block-per-row for wv ----------------
__global__ void __launch_bounds__(256) v_mat(
        const float* __restrict__ wv, const float* __restrict__ x,
        float* __restrict__ xv) {
    __shared__ float red[4];
    int row = blockIdx.x;
    const float* w = wv + (size_t)row * DIM;
    int t = threadIdx.x;
    float acc = 0.f;
#pragma unroll
    for (int i = 0; i < 4; ++i) {
        int idx = (i * 256 + t) * 4;
        const float4 a = *reinterpret_cast<const float4*>(w + idx);
        const float4 b = *reinterpret_cast<const float4*>(x + idx);
        acc = fmaf(a.x, b.x, acc);
        acc = fmaf(a.y, b.y, acc);
        acc = fmaf(a.z, b.z, acc);
        acc = fmaf(a.w, b.w, acc);
    }
#pragma unroll
    for (int off = 32; off; off >>= 1) acc += __shfl_xor(acc, off);
    if ((t & 63) == 0) red[t >> 6] = acc;
    __syncthreads();
    if (t == 0) xv[row] = red[0] + red[1] + red[2] + red[3];
}

// ---------------- out = Wo @ v : wave per row-pair, pipelined (L3-resident, fast) ----------------
__device__ __forceinline__ void load_half(v4f (&buf)[8], const float* __restrict__ wp, int off) {
#pragma unroll
    for (int i = 0; i < 8; ++i)
        buf[i] = *reinterpret_cast<const v4f*>(wp + i * 256 + off);
}

template <int XO>
__device__ __forceinline__ float dot_half(const v4f (&buf)[8], const v4f (&xr)[16]) {
    float s0 = 0.f, s1 = 0.f, s2 = 0.f, s3 = 0.f;
#pragma unroll
    for (int i = 0; i < 8; ++i) {
        s0 = fmaf(buf[i].x, xr[XO + i].x, s0);
        s1 = fmaf(buf[i].y, xr[XO + i].y, s1);
        s2 = fmaf(buf[i].z, xr[XO + i].z, s2);
        s3 = fmaf(buf[i].w, xr[XO + i].w, s3);
    }
    return (s0 + s1) + (s2 + s3);
}

#define SB() __builtin_amdgcn_sched_barrier(0)

__global__ void __launch_bounds__(256) matvec_o(
        const float* __restrict__ w_, const float* __restrict__ vin,
        float* __restrict__ y) {
    int t = threadIdx.x, lane = t & 63;
    int W = blockIdx.x * 4 + (t >> 6);      // 0..2047
    int r0 = W * 2;
    int off = lane * 4;

    v4f xr[16];
#pragma unroll
    for (int i = 0; i < 16; ++i)
        xr[i] = *reinterpret_cast<const v4f*>(vin + i * 256 + off);

    const float* w0 = w_ + (size_t)r0 * DIM;
    v4f A[8], B[8];
    float d0, d1;
    load_half(A, w0, off);
    load_half(B, w0 + 2048, off);            SB();
    d0  = dot_half<0>(A, xr);
    load_half(A, w0 + DIM, off);             SB();
    d0 += dot_half<8>(B, xr);
    load_half(B, w0 + DIM + 2048, off);      SB();
    d1  = dot_half<0>(A, xr);
    d1 += dot_half<8>(B, xr);

    d0 = wave_sum(d0); d1 = wave_sum(d1);
    if (lane == 0) { y[r0] = d0; y[r0 + 1] = d1; }
}

// ---------------- flash-decode partials ----------------
__global__ void attn_partial(const float* __restrict__ cache_k, const float* __restrict__ cache_v,
                             const float* __restrict__ xq, const float* __restrict__ xk,
                             const float* __restrict__ xv, const int* __restrict__ pos_p,
                             float* __restrict__ partials) {
    __shared__ float lds_m[4], lds_l[4];
    __shared__ float lds_acc[4][128];
    int h = blockIdx.x;
    int c = blockIdx.y;
    int lane = threadIdx.x;          // 64
    int g  = lane >> 4;              // group 0..3
    int gl = lane & 15;              // lane-in-group; owns dims gl*8 .. gl*8+7
    int pos = *pos_p;
    int base = c * CHUNK;
    int p1 = min(base + CHUNK, pos + 1);
    float* pp = partials + (size_t)(h * NCHUNK + c) * PART_STRIDE;

    if (base > pos) {   // fully inactive chunk: identity partial
        if (lane == 0) { pp[0] = -INFINITY; pp[1] = 0.f; }
        reinterpret_cast<float2*>(pp + 2)[lane] = make_float2(0.f, 0.f);
        return;
    }

    const float4* qv = reinterpret_cast<const float4*>(xq + h * D + gl * 8);
    const float4 q0 = qv[0], q1 = qv[1];

    float m = -INFINITY, l = 0.f;
    float4 acc0 = make_float4(0.f, 0.f, 0.f, 0.f);
    float4 acc1 = make_float4(0.f, 0.f, 0.f, 0.f);

    for (int p = base + g; p < p1; p += 4) {
        const float* kp = (p == pos) ? (xk + h * D)
                                     : (cache_k + ((size_t)p * H + h) * D);
        const float4* kv4 = reinterpret_cast<const float4*>(kp + gl * 8);
        float4 k0 = kv4[0], k1 = kv4[1];
        float d = q0.x * k0.x + q0.y * k0.y + q0.z * k0.z + q0.w * k0.w
                + q1.x * k1.x + q1.y * k1.y + q1.z * k1.z + q1.w * k1.w;
        d += __shfl_xor(d, 1);
        d += __shfl_xor(d, 2);
        d += __shfl_xor(d, 4);
        d += __shfl_xor(d, 8);       // all 16 lanes of the group hold the dot
        float s = d * 0.08838834764831845f;   // 1/sqrt(128)
        float mn = fmaxf(m, s);
        float corr = __expf(m - mn);          // exp(-inf)=0 on first iter
        float wgt  = __expf(s - mn);
        const float* vp = (p == pos) ? (xv + h * D)
                                     : (cache_v + ((size_t)p * H + h) * D);
        const float4* vv4 = reinterpret_cast<const float4*>(vp + gl * 8);
        float4 v0 = vv4[0], v1 = vv4[1];
        l = l * corr + wgt;
        acc0.x = fmaf(wgt, v0.x, acc0.x * corr);
        acc0.y = fmaf(wgt, v0.y, acc0.y * corr);
        acc0.z = fmaf(wgt, v0.z, acc0.z * corr);
        acc0.w = fmaf(wgt, v0.w, acc0.w * corr);
        acc1.x = fmaf(wgt, v1.x, acc1.x * corr);
        acc1.y = fmaf(wgt, v1.y, acc1.y * corr);
        acc1.z = fmaf(wgt, v1.z, acc1.z * corr);
        acc1.w = fmaf(wgt, v1.w, acc1.w * corr);
        m = mn;
    }

    // combine the 4 groups inside the block
    if (gl == 0) { lds_m[g] = m; lds_l[g] = l; }
    *reinterpret_cast<float4*>(&lds_acc[g][gl * 8])     = acc0;
    *reinterpret_cast<float4*>(&lds_acc[g][gl * 8 + 4]) = acc1;
    __syncthreads();
    float M = fmaxf(fmaxf(lds_m[0], lds_m[1]), fmaxf(lds_m[2], lds_m[3]));
    float w0 = __expf(lds_m[0] - M);
    float w1 = __expf(lds_m[1] - M);
    float w2 = __expf(lds_m[2] - M);
    float w3 = __expf(lds_m[3] - M);
    float L  = w0 * lds_l[0] + w1 * lds_l[1] + w2 * lds_l[2] + w3 * lds_l[3];
    int d0 = 2 * lane;
    float s0 = w0 * lds_acc[0][d0]     + w1 * lds_acc[1][d0]
             + w2 * lds_acc[2][d0]     + w3 * lds_acc[3][d0];
    float s1 = w0 * lds_acc[0][d0 + 1] + w1 * lds_acc[1][d0 + 1]
             + w2 * lds_acc[2][d0 + 1] + w3 * lds_acc[3][d0 + 1];
    if (lane == 0) { pp[0] = M; pp[1] = L; }
    reinterpret_cast<float2*>(pp + 2)[lane] = make_float2(s0, s1);
}

// ---------------- combine partials per head ----------------
__global__ void attn_combine(const float* __restrict__ partials, float* __restrict__ out_attn) {
    int h = blockIdx.x;
    int lane = threadIdx.x;          // 64 lanes, dims 2*lane, 2*lane+1
    float m = -INFINITY;
    for (int c = 0; c < NCHUNK; ++c)
        m = fmaxf(m, partials[(size_t)(h * NCHUNK + c) * PART_STRIDE]);
    float L = 0.f, a0 = 0.f, a1 = 0.f;
    for (int c = 0; c < NCHUNK; ++c) {
        const float* pp = partials + (size_t)(h * NCHUNK + c) * PART_STRIDE;
        float w = __expf(pp[0] - m);      // exp(-inf - m) = 0 for empty chunks
        L += pp[1] * w;
        float2 a = reinterpret_cast<const float2*>(pp + 2)[lane];
        a0 += w * a.x;
        a1 += w * a.y;
    }
    float inv = 1.f / L;
    out_attn[h * D + 2 * lane]     = a0 * inv;
    out_attn[h * D + 2 * lane + 1] = a1 * inv;
}

extern "C" void kernel_launch(void* const* d_in, const int* in_sizes, int n_in,
                              void* d_out, int out_size, void* d_ws, size_t ws_size,
                              hipStream_t stream) {
    const float* x       = (const float*)d_in[0];
    const float* wq      = (const float*)d_in[1];
    const float* wk      = (const float*)d_in[2];
    const float* wv      = (const float*)d_in[3];
    const float* wo      = (const float*)d_in[4];
    const float* cache_k = (const float*)d_in[5];
    const float* cache_v = (const float*)d_in[6];
    const int*   pos     = (const int*)d_in[7];

    float* ws       = (float*)d_ws;
    float* xq       = ws;                 // 4096
    float* xk       = ws + DIM;           // 4096
    float* xv       = ws + 2 * DIM;       // 4096
    float* partials = ws + 3 * DIM;       // 32*64*130
    float* out_attn = partials + H * NCHUNK * PART_STRIDE;  // 4096
    float* out      = (float*)d_out;

    qk_rope<<<4096, 256, 0, stream>>>(wq, wk, x, pos, xq, xk);
    v_mat<<<DIM, 256, 0, stream>>>(wv, x, xv);
    attn_partial<<<dim3(H, NCHUNK), 64, 0, stream>>>(cache_k, cache_v, xq, xk, xv, pos, partials);
    attn_combine<<<H, 64, 0, stream>>>(partials, out_attn);
    matvec_o<<<512, 256, 0, stream>>>(wo, out_attn, out);
}